// Round 5
// baseline (6140.953 us; speedup 1.0000x reference)
//
#include <hip/hip_runtime.h>

// AdaptiveDownsampling: farthest point sampling (B=8, N=8192, m=4096) + gather.
// Outputs concatenated flat: dp [8,4096,3] then df [8,4096,256], float32.
//
// r2: np reference computes in float64 -> exact path must be fp64.
// r3-r5: register-array spill / AGPR tax lessons; named scalars only.
// r6: fp32 screen + rare exact fp64 path. 5275 us.
// r7: DPP wave max, packed-fp32 screen, precomputed margin. 4239 us.
// r8: FAILED (5264): redundant block reduce in every wave. VALU issue x16.
// r9: dirty-wave caching + fused v_max_u32_dpp ladders. 4198 us.
// r10: FAILED (5165): Morton sort + sphere cull. VALU net-flat (cull test
//     ~= saved screens) and the test added latency to the pacing wave's
//     serial path. Lesson: only the slowest wave's path matters; add NOTHING
//     serial. Reverted.
// r11: chain/issue trim, zero added latency (resubmitted after GPU timeout):
//     (a) winner coords ride in the atomicMin payload: owner LANES publish
//         3x u64 (idx<<32)|coord_bits (idx unique -> exact ordering, ties
//         impossible). Kills s_pts staging (96KB), the per-wave min-index
//         ladder, and the post-B widx->coords dependent double LDS RT.
//     (b) screen trigger consolidated: packed t = d - mfm, min-tree, ONE
//         rare branch instead of 8 exec-mask regions (fp32 subtract sign
//         exactly preserves d < mfm: diff of two floats never rounds to 0).

typedef float v2f __attribute__((ext_vector_type(2)));

#define BATCH 8
#define NPTS  8192
#define MSEL  4096
#define NFEAT 256
#define BLOCK 1024

// fp64 square, opaque to the compiler so no v_fma_f64 contraction can merge
// the following adds (numpy float64 does separate mul / add / add).
__device__ __forceinline__ double sqd(double x) {
    double r;
    asm("v_mul_f64 %0, %1, %1" : "=v"(r) : "v"(x));
    return r;
}

// Exact 64-lane u32 max via fused DPP max ops, result wave-uniform in SGPR.
// bound_ctrl:0 => out-of-range DPP sources read 0 (identity for unsigned max).
// Requires full exec / uniform control flow at the call site.
__device__ __forceinline__ unsigned wave_umax_rl(unsigned v) {
    unsigned s;
    asm volatile(
        "s_nop 1\n\t"
        "v_max_u32_dpp %1, %1, %1 row_shr:1  row_mask:0xf bank_mask:0xf bound_ctrl:0\n\t"
        "s_nop 1\n\t"
        "v_max_u32_dpp %1, %1, %1 row_shr:2  row_mask:0xf bank_mask:0xf bound_ctrl:0\n\t"
        "s_nop 1\n\t"
        "v_max_u32_dpp %1, %1, %1 row_shr:4  row_mask:0xf bank_mask:0xf bound_ctrl:0\n\t"
        "s_nop 1\n\t"
        "v_max_u32_dpp %1, %1, %1 row_shr:8  row_mask:0xf bank_mask:0xf bound_ctrl:0\n\t"
        "s_nop 1\n\t"
        "v_max_u32_dpp %1, %1, %1 row_bcast:15 row_mask:0xf bank_mask:0xf bound_ctrl:0\n\t"
        "s_nop 1\n\t"
        "v_max_u32_dpp %1, %1, %1 row_bcast:31 row_mask:0xf bank_mask:0xf bound_ctrl:0\n\t"
        "s_nop 1\n\t"
        "v_readlane_b32 %0, %1, 63"
        : "=s"(s), "+v"(v));
    return s;
}

__launch_bounds__(BLOCK, 1)
__global__ void fps_kernel(const float* __restrict__ pts,   // [B, N, 3]
                           float* __restrict__ dp,          // [B, M, 3]
                           int* __restrict__ idx_out)       // [B, M]
{
    __shared__ unsigned long long s_bmax[2];      // block max, double bits (nonneg)
    __shared__ unsigned long long s_pay[2][3];    // (idx<<32)|coord_bits, atomicMin

    const int b    = blockIdx.x;
    const int tid  = threadIdx.x;
    const int lane = tid & 63;
    const float* p = pts + (size_t)b * NPTS * 3;

    if (tid == 0) {
        s_bmax[0] = 0ull;  s_bmax[1] = 0ull;
        s_pay[0][0] = ~0ull; s_pay[0][1] = ~0ull; s_pay[0][2] = ~0ull;
        s_pay[1][0] = ~0ull; s_pay[1][1] = ~0ull; s_pay[1][2] = ~0ull;
    }

    // Coords as float2 pairs (slots 2P, 2P+1) -> packed-fp32 screen.
    // mind (fp64 exact) + mfm (pre-margined fp32 screen threshold) per slot,
    // mfm kept packed per pair for the consolidated trigger.
#define DECLP(P, J0, J1) \
    v2f pxp##P = { p[(tid + J0 * 1024) * 3 + 0], p[(tid + J1 * 1024) * 3 + 0] }; \
    v2f pyp##P = { p[(tid + J0 * 1024) * 3 + 1], p[(tid + J1 * 1024) * 3 + 1] }; \
    v2f pzp##P = { p[(tid + J0 * 1024) * 3 + 2], p[(tid + J1 * 1024) * 3 + 2] };
    DECLP(0, 0, 1) DECLP(1, 2, 3) DECLP(2, 4, 5) DECLP(3, 6, 7)
#undef DECLP
    double mind0 = 1e10, mind1 = 1e10, mind2 = 1e10, mind3 = 1e10;
    double mind4 = 1e10, mind5 = 1e10, mind6 = 1e10, mind7 = 1e10;
    v2f mfm01 = {1.0001e10f, 1.0001e10f}, mfm23 = {1.0001e10f, 1.0001e10f};
    v2f mfm45 = {1.0001e10f, 1.0001e10f}, mfm67 = {1.0001e10f, 1.0001e10f};

    // Selection 0 is point 0 (deterministic start).
    float cx = p[0], cy = p[1], cz = p[2];
    if (tid == 0) {
        dp[(size_t)b * MSEL * 3 + 0] = cx;
        dp[(size_t)b * MSEL * 3 + 1] = cy;
        dp[(size_t)b * MSEL * 3 + 2] = cz;
        idx_out[b * MSEL + 0] = 0;
    }

    double   tbv   = 0.0;          // cached thread-local max of mind0..7
    bool     dirty = true;         // lane updated since last wave reduce
    unsigned whi = 0u, wlo = 0u;   // cached wave max (double bits), SGPR
    unsigned nidx = 0xffffffffu;   // per-lane min global idx at wave max
    float    nx = 0.f, ny = 0.f, nz = 0.f;   // coords of that point

    __syncthreads();   // slot inits visible

    for (int k = 1; k < MSEL; ++k) {
        const v2f cx2 = {cx, cx}, cy2 = {cy, cy}, cz2 = {cz, cz};

        // --- packed fp32 screen, consolidated single-branch trigger ---
        const v2f dxa = pxp0 - cx2, dya = pyp0 - cy2, dza = pzp0 - cz2;
        const v2f d0  = dxa * dxa + dya * dya + dza * dza;
        const v2f dxb = pxp1 - cx2, dyb = pyp1 - cy2, dzb = pzp1 - cz2;
        const v2f d1  = dxb * dxb + dyb * dyb + dzb * dzb;
        const v2f dxc = pxp2 - cx2, dyc = pyp2 - cy2, dzc = pzp2 - cz2;
        const v2f d2  = dxc * dxc + dyc * dyc + dzc * dzc;
        const v2f dxd = pxp3 - cx2, dyd = pyp3 - cy2, dzd = pzp3 - cz2;
        const v2f d3  = dxd * dxd + dyd * dyd + dzd * dzd;
        const v2f t0 = d0 - mfm01, t1 = d1 - mfm23;
        const v2f t2 = d2 - mfm45, t3 = d3 - mfm67;
        const float mtx = fminf(fminf(t0.x, t1.x), fminf(t2.x, t3.x));
        const float mty = fminf(fminf(t0.y, t1.y), fminf(t2.y, t3.y));

        if (mtx < 0.f || mty < 0.f) {   // rare mid/late-run: exact fp64 updates
#define EX64(PX, PY, PZ, MIND, MFE) { \
            const double ddx = (double)(PX) - (double)cx; \
            const double ddy = (double)(PY) - (double)cy; \
            const double ddz = (double)(PZ) - (double)cz; \
            const double dd  = (sqd(ddx) + sqd(ddy)) + sqd(ddz); \
            if (dd < MIND) { MIND = dd; MFE = (float)dd * 1.0001f; dirty = true; } }
            if (t0.x < 0.f) EX64(pxp0.x, pyp0.x, pzp0.x, mind0, mfm01.x)
            if (t0.y < 0.f) EX64(pxp0.y, pyp0.y, pzp0.y, mind1, mfm01.y)
            if (t1.x < 0.f) EX64(pxp1.x, pyp1.x, pzp1.x, mind2, mfm23.x)
            if (t1.y < 0.f) EX64(pxp1.y, pyp1.y, pzp1.y, mind3, mfm23.y)
            if (t2.x < 0.f) EX64(pxp2.x, pyp2.x, pzp2.x, mind4, mfm45.x)
            if (t2.y < 0.f) EX64(pxp2.y, pyp2.y, pzp2.y, mind5, mfm45.y)
            if (t3.x < 0.f) EX64(pxp3.x, pyp3.x, pzp3.x, mind6, mfm67.x)
            if (t3.y < 0.f) EX64(pxp3.y, pyp3.y, pzp3.y, mind7, mfm67.y)
#undef EX64
        }

        // --- wave reduce only if some lane in this wave updated ---
        if (__any(dirty)) {
            const double a0 = fmax(mind0, mind1), a1 = fmax(mind2, mind3);
            const double a2 = fmax(mind4, mind5), a3 = fmax(mind6, mind7);
            tbv = fmax(fmax(a0, a1), fmax(a2, a3));
            dirty = false;

            const unsigned long long tb = (unsigned long long)__double_as_longlong(tbv);
            const unsigned thi = (unsigned)(tb >> 32);
            const unsigned tlo = (unsigned)tb;
            whi = wave_umax_rl(thi);
            wlo = wave_umax_rl(thi == whi ? tlo : 0u);

            // per-lane min global idx among this lane's slots at the wave max
            // (numpy tie-break: scan high slot -> low, smallest wins last),
            // capturing that point's coords for the payload publish.
            nidx = 0xffffffffu;
            if (thi == whi && tlo == wlo) {
                if (mind7 == tbv) { nidx = tid + 7*1024; nx = pxp3.y; ny = pyp3.y; nz = pzp3.y; }
                if (mind6 == tbv) { nidx = tid + 6*1024; nx = pxp3.x; ny = pyp3.x; nz = pzp3.x; }
                if (mind5 == tbv) { nidx = tid + 5*1024; nx = pxp2.y; ny = pyp2.y; nz = pzp2.y; }
                if (mind4 == tbv) { nidx = tid + 4*1024; nx = pxp2.x; ny = pyp2.x; nz = pzp2.x; }
                if (mind3 == tbv) { nidx = tid + 3*1024; nx = pxp1.y; ny = pyp1.y; nz = pzp1.y; }
                if (mind2 == tbv) { nidx = tid + 2*1024; nx = pxp1.x; ny = pyp1.x; nz = pzp1.x; }
                if (mind1 == tbv) { nidx = tid + 1*1024; nx = pxp0.y; ny = pyp0.y; nz = pzp0.y; }
                if (mind0 == tbv) { nidx = tid;          nx = pxp0.x; ny = pyp0.x; nz = pzp0.x; }
            }
        }

        const unsigned long long mybits =
            ((unsigned long long)whi << 32) | (unsigned long long)wlo;
        const int buf = k & 1;
        if (lane == 0) atomicMax(&s_bmax[buf], mybits);
        __syncthreads();                                   // barrier A

        const unsigned long long bmaxbits = s_bmax[buf];
        if (tid == 0) {   // reset NEXT iter's slots (between barriers A and B)
            s_bmax[buf ^ 1] = 0ull;
            s_pay[buf ^ 1][0] = ~0ull;
            s_pay[buf ^ 1][1] = ~0ull;
            s_pay[buf ^ 1][2] = ~0ull;
        }

        // --- owner lanes publish (idx, coords) directly; min idx wins.
        //     idx unique per lane-slot -> exact, tie-free ordering. ---
        if (mybits == bmaxbits && nidx != 0xffffffffu) {
            const unsigned long long hi = (unsigned long long)nidx << 32;
            atomicMin(&s_pay[buf][0], hi | (unsigned long long)__float_as_uint(nx));
            atomicMin(&s_pay[buf][1], hi | (unsigned long long)__float_as_uint(ny));
            atomicMin(&s_pay[buf][2], hi | (unsigned long long)__float_as_uint(nz));
        }
        __syncthreads();                                   // barrier B

        // --- single parallel LDS round-trip: idx + coords from payloads ---
        const unsigned long long p0 = s_pay[buf][0];
        const unsigned long long p1 = s_pay[buf][1];
        const unsigned long long p2 = s_pay[buf][2];
        const int   widx = (int)(p0 >> 32);
        const float wx = __uint_as_float((unsigned)p0);
        const float wy = __uint_as_float((unsigned)p1);
        const float wz = __uint_as_float((unsigned)p2);
        if (tid == 0) {
            idx_out[b * MSEL + k] = widx;
            float* o = dp + ((size_t)b * MSEL + k) * 3;
            o[0] = wx; o[1] = wy; o[2] = wz;
        }
        cx = wx; cy = wy; cz = wz;
    }
}

// One wave per selected row; lane i moves one float4 (64 * 16B = 1024B = full row).
__global__ void gather_kernel(const float* __restrict__ feats,  // [B, N, C]
                              const int* __restrict__ idx,      // [B, M]
                              float* __restrict__ df)           // [B, M, C]
{
    const int row  = blockIdx.x * 4 + (threadIdx.x >> 6);  // [0, B*M)
    const int lane = threadIdx.x & 63;
    const int b    = row >> 12;         // MSEL = 4096 rows per batch
    const int src  = idx[row];
    const float4* s = (const float4*)(feats + ((size_t)b * NPTS + src) * NFEAT);
    float4*       d = (float4*)(df + (size_t)row * NFEAT);
    d[lane] = s[lane];
}

extern "C" void kernel_launch(void* const* d_in, const int* in_sizes, int n_in,
                              void* d_out, int out_size, void* d_ws, size_t ws_size,
                              hipStream_t stream)
{
    const float* points   = (const float*)d_in[0];   // [8, 8192, 3]
    const float* features = (const float*)d_in[1];   // [8, 8192, 256]
    float* out = (float*)d_out;
    float* dp  = out;                                // [8, 4096, 3]
    float* df  = out + (size_t)BATCH * MSEL * 3;     // [8, 4096, 256]
    int*   idx_ws = (int*)d_ws;                      // [8, 4096] = 128 KB scratch

    fps_kernel<<<BATCH, BLOCK, 0, stream>>>(points, dp, idx_ws);
    gather_kernel<<<(BATCH * MSEL) / 4, 256, 0, stream>>>(features, idx_ws, df);
}

// Round 6
// 5532.141 us; speedup vs baseline: 1.1100x; 1.1100x over previous
//
#include <hip/hip_runtime.h>

// AdaptiveDownsampling: farthest point sampling (B=8, N=8192, m=4096) + gather.
// Outputs concatenated flat: dp [8,4096,3] then df [8,4096,256], float32.
//
// r2: np reference computes in float64 -> exact path must be fp64.
// r3-r5: register-array spill / AGPR tax lessons; named scalars only.
// r6: fp32 screen + rare exact fp64 path. 5275 us.
// r7: DPP wave max, packed-fp32 screen, precomputed margin. 4239 us.
// r8: FAILED (5264): redundant block reduce in every wave. VALU issue x16.
// r9: dirty-wave caching + fused v_max_u32_dpp ladders. 4198 us (BEST).
// r10: FAILED (5165): Morton sort + sphere cull. Serial cull test on the
//     pacing path ~= saved screen work. Add NOTHING serial.
// r11: FAILED (6141): payload-atomics + wide trigger => VGPR-64 cliff,
//     scratch spills (FETCH 424->840KB, WRITE 512->1344KB, stall-dominated).
//     Lesson: hold peak register liveness flat; this loop sits on a cliff.
// r12: r9 skeleton + liveness-neutral cuts on the pacing wave's chain:
//     (a) running-min screen trigger (temps die per-pair; ONE rare branch;
//         rare path re-screens scalar per slot -- margin makes it sound);
//     (b) owner LANES atomicMin their cached min-idx directly (kills the
//         3rd DPP ladder; exact numpy min-index unchanged);
//     (c) wlo via ballot: if exactly one lane holds hi-max (common), read
//         its lo32 with v_readlane (~5 scalar ops) instead of ladder 2;
//         exact ladder fallback on multi-lane hi ties.

typedef float v2f __attribute__((ext_vector_type(2)));

#define BATCH 8
#define NPTS  8192
#define MSEL  4096
#define NFEAT 256
#define BLOCK 1024

// fp64 square, opaque to the compiler so no v_fma_f64 contraction can merge
// the following adds (numpy float64 does separate mul / add / add).
__device__ __forceinline__ double sqd(double x) {
    double r;
    asm("v_mul_f64 %0, %1, %1" : "=v"(r) : "v"(x));
    return r;
}

// Exact 64-lane u32 max via fused DPP max ops, result wave-uniform in SGPR.
// bound_ctrl:0 => out-of-range DPP sources read 0 (identity for unsigned max).
// Requires full exec / uniform control flow at the call site.
__device__ __forceinline__ unsigned wave_umax_rl(unsigned v) {
    unsigned s;
    asm volatile(
        "s_nop 1\n\t"
        "v_max_u32_dpp %1, %1, %1 row_shr:1  row_mask:0xf bank_mask:0xf bound_ctrl:0\n\t"
        "s_nop 1\n\t"
        "v_max_u32_dpp %1, %1, %1 row_shr:2  row_mask:0xf bank_mask:0xf bound_ctrl:0\n\t"
        "s_nop 1\n\t"
        "v_max_u32_dpp %1, %1, %1 row_shr:4  row_mask:0xf bank_mask:0xf bound_ctrl:0\n\t"
        "s_nop 1\n\t"
        "v_max_u32_dpp %1, %1, %1 row_shr:8  row_mask:0xf bank_mask:0xf bound_ctrl:0\n\t"
        "s_nop 1\n\t"
        "v_max_u32_dpp %1, %1, %1 row_bcast:15 row_mask:0xf bank_mask:0xf bound_ctrl:0\n\t"
        "s_nop 1\n\t"
        "v_max_u32_dpp %1, %1, %1 row_bcast:31 row_mask:0xf bank_mask:0xf bound_ctrl:0\n\t"
        "s_nop 1\n\t"
        "v_readlane_b32 %0, %1, 63"
        : "=s"(s), "+v"(v));
    return s;
}

__launch_bounds__(BLOCK, 1)
__global__ void fps_kernel(const float* __restrict__ pts,   // [B, N, 3]
                           float* __restrict__ dp,          // [B, M, 3]
                           int* __restrict__ idx_out)       // [B, M]
{
    __shared__ float s_pts[NPTS * 3];          // 96 KB fp32 copy (winner broadcast)
    __shared__ unsigned long long s_bmax[2];   // block max, double bits (nonneg)
    __shared__ int s_widx[2];                  // winner index via atomicMin

    const int b    = blockIdx.x;
    const int tid  = threadIdx.x;
    const int lane = tid & 63;
    const float* p = pts + (size_t)b * NPTS * 3;

    for (int i = tid; i < NPTS * 3; i += BLOCK) s_pts[i] = p[i];
    if (tid == 0) {
        s_bmax[0] = 0ull;        s_bmax[1] = 0ull;
        s_widx[0] = 0x7fffffff;  s_widx[1] = 0x7fffffff;
    }

    // Coords as float2 pairs (slots 2P, 2P+1) -> packed-fp32 screen.
    // mind (fp64 exact) + mfm (pre-margined fp32 screen threshold, packed).
#define DECLP(P, J0, J1) \
    v2f pxp##P = { p[(tid + J0 * 1024) * 3 + 0], p[(tid + J1 * 1024) * 3 + 0] }; \
    v2f pyp##P = { p[(tid + J0 * 1024) * 3 + 1], p[(tid + J1 * 1024) * 3 + 1] }; \
    v2f pzp##P = { p[(tid + J0 * 1024) * 3 + 2], p[(tid + J1 * 1024) * 3 + 2] };
    DECLP(0, 0, 1) DECLP(1, 2, 3) DECLP(2, 4, 5) DECLP(3, 6, 7)
#undef DECLP
    double mind0 = 1e10, mind1 = 1e10, mind2 = 1e10, mind3 = 1e10;
    double mind4 = 1e10, mind5 = 1e10, mind6 = 1e10, mind7 = 1e10;
    v2f mfm01 = {1.0001e10f, 1.0001e10f}, mfm23 = {1.0001e10f, 1.0001e10f};
    v2f mfm45 = {1.0001e10f, 1.0001e10f}, mfm67 = {1.0001e10f, 1.0001e10f};

    // Selection 0 is point 0 (deterministic start).
    float cx = p[0], cy = p[1], cz = p[2];
    if (tid == 0) {
        dp[(size_t)b * MSEL * 3 + 0] = cx;
        dp[(size_t)b * MSEL * 3 + 1] = cy;
        dp[(size_t)b * MSEL * 3 + 2] = cz;
        idx_out[b * MSEL + 0] = 0;
    }

    double   tbv   = 0.0;          // cached thread-local max of mind0..7
    bool     dirty = true;         // lane updated since last wave reduce
    unsigned whi = 0u, wlo = 0u;   // cached wave max (double bits), SGPR
    unsigned n   = 0x7fffffffu;    // cached per-lane min idx at wave max

    __syncthreads();   // s_pts + slot inits visible

    for (int k = 1; k < MSEL; ++k) {
        const v2f cx2 = {cx, cx}, cy2 = {cy, cy}, cz2 = {cz, cz};

        // --- packed fp32 screen: running min of (d - mfm); temps die per pair ---
        float mtx, mty;
        {
            const v2f dx = pxp0 - cx2, dy = pyp0 - cy2, dz = pzp0 - cz2;
            const v2f t  = (dx * dx + dy * dy + dz * dz) - mfm01;
            mtx = t.x; mty = t.y;
        }
        {
            const v2f dx = pxp1 - cx2, dy = pyp1 - cy2, dz = pzp1 - cz2;
            const v2f t  = (dx * dx + dy * dy + dz * dz) - mfm23;
            mtx = fminf(mtx, t.x); mty = fminf(mty, t.y);
        }
        {
            const v2f dx = pxp2 - cx2, dy = pyp2 - cy2, dz = pzp2 - cz2;
            const v2f t  = (dx * dx + dy * dy + dz * dz) - mfm45;
            mtx = fminf(mtx, t.x); mty = fminf(mty, t.y);
        }
        {
            const v2f dx = pxp3 - cx2, dy = pyp3 - cy2, dz = pzp3 - cz2;
            const v2f t  = (dx * dx + dy * dy + dz * dz) - mfm67;
            mtx = fminf(mtx, t.x); mty = fminf(mty, t.y);
        }

        if (fminf(mtx, mty) < 0.f) {   // rare: scalar re-screen + exact fp64
#define EXS(PX, PY, PZ, MIND, MFMREF) { \
            const float fdx = (PX) - cx, fdy = (PY) - cy, fdz = (PZ) - cz; \
            if (fdx * fdx + fdy * fdy + fdz * fdz < MFMREF) { \
                const double ddx = (double)(PX) - (double)cx; \
                const double ddy = (double)(PY) - (double)cy; \
                const double ddz = (double)(PZ) - (double)cz; \
                const double dd  = (sqd(ddx) + sqd(ddy)) + sqd(ddz); \
                if (dd < MIND) { MIND = dd; MFMREF = (float)dd * 1.0001f; dirty = true; } } }
            EXS(pxp0.x, pyp0.x, pzp0.x, mind0, mfm01.x)
            EXS(pxp0.y, pyp0.y, pzp0.y, mind1, mfm01.y)
            EXS(pxp1.x, pyp1.x, pzp1.x, mind2, mfm23.x)
            EXS(pxp1.y, pyp1.y, pzp1.y, mind3, mfm23.y)
            EXS(pxp2.x, pyp2.x, pzp2.x, mind4, mfm45.x)
            EXS(pxp2.y, pyp2.y, pzp2.y, mind5, mfm45.y)
            EXS(pxp3.x, pyp3.x, pzp3.x, mind6, mfm67.x)
            EXS(pxp3.y, pyp3.y, pzp3.y, mind7, mfm67.y)
#undef EXS
        }

        // --- wave reduce only if some lane in this wave updated ---
        if (__any(dirty)) {
            const double a0 = fmax(mind0, mind1), a1 = fmax(mind2, mind3);
            const double a2 = fmax(mind4, mind5), a3 = fmax(mind6, mind7);
            tbv = fmax(fmax(a0, a1), fmax(a2, a3));
            dirty = false;

            const unsigned long long tb = (unsigned long long)__double_as_longlong(tbv);
            const unsigned thi = (unsigned)(tb >> 32);
            const unsigned tlo = (unsigned)tb;
            whi = wave_umax_rl(thi);

            // lo32: usually exactly one lane holds the hi-max -> readlane its
            // lo32 (scalar ops); exact ladder only on multi-lane hi ties.
            const unsigned long long own = __ballot(thi == whi);
            if (__popcll(own) == 1) {
                wlo = (unsigned)__builtin_amdgcn_readlane(
                          (int)tlo, (int)(__ffsll((unsigned long long)own) - 1));
            } else {
                wlo = wave_umax_rl(thi == whi ? tlo : 0u);
            }

            // per-lane min global idx among this lane's slots at the wave max
            // (numpy tie-break: scan high slot -> low, smallest wins last).
            n = 0x7fffffffu;
            if (thi == whi && tlo == wlo) {
                if (mind7 == tbv) n = tid + 7 * 1024;
                if (mind6 == tbv) n = tid + 6 * 1024;
                if (mind5 == tbv) n = tid + 5 * 1024;
                if (mind4 == tbv) n = tid + 4 * 1024;
                if (mind3 == tbv) n = tid + 3 * 1024;
                if (mind2 == tbv) n = tid + 2 * 1024;
                if (mind1 == tbv) n = tid + 1 * 1024;
                if (mind0 == tbv) n = tid;
            }
        }

        const unsigned long long mybits =
            ((unsigned long long)whi << 32) | (unsigned long long)wlo;
        const int buf = k & 1;
        if (lane == 0) atomicMax(&s_bmax[buf], mybits);
        __syncthreads();                                   // barrier A

        const unsigned long long bmaxbits = s_bmax[buf];
        if (tid == 0) {   // reset NEXT iter's slots (between barriers A and B)
            s_bmax[buf ^ 1] = 0ull;
            s_widx[buf ^ 1] = 0x7fffffff;
        }

        // --- owner LANES publish cached min idx directly (1-2 lanes typ.) ---
        if (mybits == bmaxbits && n != 0x7fffffffu)
            atomicMin(&s_widx[buf], (int)n);
        __syncthreads();                                   // barrier B

        // --- broadcast winner coords from LDS (same-addr = conflict-free) ---
        const int   widx = s_widx[buf];
        const float wx = s_pts[widx * 3 + 0];
        const float wy = s_pts[widx * 3 + 1];
        const float wz = s_pts[widx * 3 + 2];
        if (tid == 0) {
            idx_out[b * MSEL + k] = widx;
            float* o = dp + ((size_t)b * MSEL + k) * 3;
            o[0] = wx; o[1] = wy; o[2] = wz;
        }
        cx = wx; cy = wy; cz = wz;
    }
}

// One wave per selected row; lane i moves one float4 (64 * 16B = 1024B = full row).
__global__ void gather_kernel(const float* __restrict__ feats,  // [B, N, C]
                              const int* __restrict__ idx,      // [B, M]
                              float* __restrict__ df)           // [B, M, C]
{
    const int row  = blockIdx.x * 4 + (threadIdx.x >> 6);  // [0, B*M)
    const int lane = threadIdx.x & 63;
    const int b    = row >> 12;         // MSEL = 4096 rows per batch
    const int src  = idx[row];
    const float4* s = (const float4*)(feats + ((size_t)b * NPTS + src) * NFEAT);
    float4*       d = (float4*)(df + (size_t)row * NFEAT);
    d[lane] = s[lane];
}

extern "C" void kernel_launch(void* const* d_in, const int* in_sizes, int n_in,
                              void* d_out, int out_size, void* d_ws, size_t ws_size,
                              hipStream_t stream)
{
    const float* points   = (const float*)d_in[0];   // [8, 8192, 3]
    const float* features = (const float*)d_in[1];   // [8, 8192, 256]
    float* out = (float*)d_out;
    float* dp  = out;                                // [8, 4096, 3]
    float* df  = out + (size_t)BATCH * MSEL * 3;     // [8, 4096, 256]
    int*   idx_ws = (int*)d_ws;                      // [8, 4096] = 128 KB scratch

    fps_kernel<<<BATCH, BLOCK, 0, stream>>>(points, dp, idx_ws);
    gather_kernel<<<(BATCH * MSEL) / 4, 256, 0, stream>>>(features, idx_ws, df);
}

// Round 10
// 5517.930 us; speedup vs baseline: 1.1129x; 1.0026x over previous
//
#include <hip/hip_runtime.h>

// AdaptiveDownsampling: farthest point sampling (B=8, N=8192, m=4096) + gather.
// Outputs concatenated flat: dp [8,4096,3] then df [8,4096,256], float32.
//
// r2: np reference computes in float64 -> exact path must be fp64.
// r3-r5: register-array spill / AGPR tax lessons; named scalars only.
// r6: fp32 screen + rare exact fp64 path. 5275 us.
// r7: DPP wave max, packed-fp32 screen, precomputed margin. 4239 us.
// r8: FAILED (5264): redundant block reduce in every wave. VALU issue x16.
// r9: dirty-wave caching + fused v_max_u32_dpp ladders. 4198 us (BEST).
//     Clean baseline counters: FETCH 424 KB / WRITE 512 KB, VGPR 64.
// r10: FAILED (5165): Morton sort + sphere cull on the pacing path.
// r11: FAILED (6141): payload atomics; FETCH/WRITE ballooned -> scratch spill.
// r12: FAILED (5532): liveness-neutral intent, but FETCH 526/WRITE 704 =>
//     STILL spilling. Diagnosis: allocator pins VGPR=64 and spills anything
//     over. NOTE: r12 had __launch_bounds__(BLOCK, 1) -- a waves/EU MINIMUM
//     of 1 -- and that did NOT unlock the budget; the allocator's occupancy
//     TARGET stayed at its 8-waves/EU default.
// r13: same code + __attribute__((amdgpu_waves_per_eu(4, 4))): the MAX=4
//     bound is the operative part -- it pins the allocator's occupancy
//     target to the hardware-forced 4 waves/EU (grid=8 x 1024thr, 1
//     block/CU), raising the VGPR cap to 128 so r12's live set fits and
//     spills vanish. Then r12's real gains (ladder-3 deleted, ballot
//     shortcut for ladder 2, one-branch running-min screen) can show.
//     (Fourth submit: GPU acquisition timed out three times.)

typedef float v2f __attribute__((ext_vector_type(2)));

#define BATCH 8
#define NPTS  8192
#define MSEL  4096
#define NFEAT 256
#define BLOCK 1024

// fp64 square, opaque to the compiler so no v_fma_f64 contraction can merge
// the following adds (numpy float64 does separate mul / add / add).
__device__ __forceinline__ double sqd(double x) {
    double r;
    asm("v_mul_f64 %0, %1, %1" : "=v"(r) : "v"(x));
    return r;
}

// Exact 64-lane u32 max via fused DPP max ops, result wave-uniform in SGPR.
// bound_ctrl:0 => out-of-range DPP sources read 0 (identity for unsigned max).
// Requires full exec / uniform control flow at the call site.
__device__ __forceinline__ unsigned wave_umax_rl(unsigned v) {
    unsigned s;
    asm volatile(
        "s_nop 1\n\t"
        "v_max_u32_dpp %1, %1, %1 row_shr:1  row_mask:0xf bank_mask:0xf bound_ctrl:0\n\t"
        "s_nop 1\n\t"
        "v_max_u32_dpp %1, %1, %1 row_shr:2  row_mask:0xf bank_mask:0xf bound_ctrl:0\n\t"
        "s_nop 1\n\t"
        "v_max_u32_dpp %1, %1, %1 row_shr:4  row_mask:0xf bank_mask:0xf bound_ctrl:0\n\t"
        "s_nop 1\n\t"
        "v_max_u32_dpp %1, %1, %1 row_shr:8  row_mask:0xf bank_mask:0xf bound_ctrl:0\n\t"
        "s_nop 1\n\t"
        "v_max_u32_dpp %1, %1, %1 row_bcast:15 row_mask:0xf bank_mask:0xf bound_ctrl:0\n\t"
        "s_nop 1\n\t"
        "v_max_u32_dpp %1, %1, %1 row_bcast:31 row_mask:0xf bank_mask:0xf bound_ctrl:0\n\t"
        "s_nop 1\n\t"
        "v_readlane_b32 %0, %1, 63"
        : "=s"(s), "+v"(v));
    return s;
}

__launch_bounds__(BLOCK)
__attribute__((amdgpu_waves_per_eu(4, 4)))
__global__ void fps_kernel(const float* __restrict__ pts,   // [B, N, 3]
                           float* __restrict__ dp,          // [B, M, 3]
                           int* __restrict__ idx_out)       // [B, M]
{
    __shared__ float s_pts[NPTS * 3];          // 96 KB fp32 copy (winner broadcast)
    __shared__ unsigned long long s_bmax[2];   // block max, double bits (nonneg)
    __shared__ int s_widx[2];                  // winner index via atomicMin

    const int b    = blockIdx.x;
    const int tid  = threadIdx.x;
    const int lane = tid & 63;
    const float* p = pts + (size_t)b * NPTS * 3;

    for (int i = tid; i < NPTS * 3; i += BLOCK) s_pts[i] = p[i];
    if (tid == 0) {
        s_bmax[0] = 0ull;        s_bmax[1] = 0ull;
        s_widx[0] = 0x7fffffff;  s_widx[1] = 0x7fffffff;
    }

    // Coords as float2 pairs (slots 2P, 2P+1) -> packed-fp32 screen.
    // mind (fp64 exact) + mfm (pre-margined fp32 screen threshold, packed).
#define DECLP(P, J0, J1) \
    v2f pxp##P = { p[(tid + J0 * 1024) * 3 + 0], p[(tid + J1 * 1024) * 3 + 0] }; \
    v2f pyp##P = { p[(tid + J0 * 1024) * 3 + 1], p[(tid + J1 * 1024) * 3 + 1] }; \
    v2f pzp##P = { p[(tid + J0 * 1024) * 3 + 2], p[(tid + J1 * 1024) * 3 + 2] };
    DECLP(0, 0, 1) DECLP(1, 2, 3) DECLP(2, 4, 5) DECLP(3, 6, 7)
#undef DECLP
    double mind0 = 1e10, mind1 = 1e10, mind2 = 1e10, mind3 = 1e10;
    double mind4 = 1e10, mind5 = 1e10, mind6 = 1e10, mind7 = 1e10;
    v2f mfm01 = {1.0001e10f, 1.0001e10f}, mfm23 = {1.0001e10f, 1.0001e10f};
    v2f mfm45 = {1.0001e10f, 1.0001e10f}, mfm67 = {1.0001e10f, 1.0001e10f};

    // Selection 0 is point 0 (deterministic start).
    float cx = p[0], cy = p[1], cz = p[2];
    if (tid == 0) {
        dp[(size_t)b * MSEL * 3 + 0] = cx;
        dp[(size_t)b * MSEL * 3 + 1] = cy;
        dp[(size_t)b * MSEL * 3 + 2] = cz;
        idx_out[b * MSEL + 0] = 0;
    }

    double   tbv   = 0.0;          // cached thread-local max of mind0..7
    bool     dirty = true;         // lane updated since last wave reduce
    unsigned whi = 0u, wlo = 0u;   // cached wave max (double bits), SGPR
    unsigned n   = 0x7fffffffu;    // cached per-lane min idx at wave max

    __syncthreads();   // s_pts + slot inits visible

    for (int k = 1; k < MSEL; ++k) {
        const v2f cx2 = {cx, cx}, cy2 = {cy, cy}, cz2 = {cz, cz};

        // --- packed fp32 screen: running min of (d - mfm); temps die per pair ---
        float mtx, mty;
        {
            const v2f dx = pxp0 - cx2, dy = pyp0 - cy2, dz = pzp0 - cz2;
            const v2f t  = (dx * dx + dy * dy + dz * dz) - mfm01;
            mtx = t.x; mty = t.y;
        }
        {
            const v2f dx = pxp1 - cx2, dy = pyp1 - cy2, dz = pzp1 - cz2;
            const v2f t  = (dx * dx + dy * dy + dz * dz) - mfm23;
            mtx = fminf(mtx, t.x); mty = fminf(mty, t.y);
        }
        {
            const v2f dx = pxp2 - cx2, dy = pyp2 - cy2, dz = pzp2 - cz2;
            const v2f t  = (dx * dx + dy * dy + dz * dz) - mfm45;
            mtx = fminf(mtx, t.x); mty = fminf(mty, t.y);
        }
        {
            const v2f dx = pxp3 - cx2, dy = pyp3 - cy2, dz = pzp3 - cz2;
            const v2f t  = (dx * dx + dy * dy + dz * dz) - mfm67;
            mtx = fminf(mtx, t.x); mty = fminf(mty, t.y);
        }

        if (fminf(mtx, mty) < 0.f) {   // rare: scalar re-screen + exact fp64
#define EXS(PX, PY, PZ, MIND, MFMREF) { \
            const float fdx = (PX) - cx, fdy = (PY) - cy, fdz = (PZ) - cz; \
            if (fdx * fdx + fdy * fdy + fdz * fdz < MFMREF) { \
                const double ddx = (double)(PX) - (double)cx; \
                const double ddy = (double)(PY) - (double)cy; \
                const double ddz = (double)(PZ) - (double)cz; \
                const double dd  = (sqd(ddx) + sqd(ddy)) + sqd(ddz); \
                if (dd < MIND) { MIND = dd; MFMREF = (float)dd * 1.0001f; dirty = true; } } }
            EXS(pxp0.x, pyp0.x, pzp0.x, mind0, mfm01.x)
            EXS(pxp0.y, pyp0.y, pzp0.y, mind1, mfm01.y)
            EXS(pxp1.x, pyp1.x, pzp1.x, mind2, mfm23.x)
            EXS(pxp1.y, pyp1.y, pzp1.y, mind3, mfm23.y)
            EXS(pxp2.x, pyp2.x, pzp2.x, mind4, mfm45.x)
            EXS(pxp2.y, pyp2.y, pzp2.y, mind5, mfm45.y)
            EXS(pxp3.x, pyp3.x, pzp3.x, mind6, mfm67.x)
            EXS(pxp3.y, pyp3.y, pzp3.y, mind7, mfm67.y)
#undef EXS
        }

        // --- wave reduce only if some lane in this wave updated ---
        if (__any(dirty)) {
            const double a0 = fmax(mind0, mind1), a1 = fmax(mind2, mind3);
            const double a2 = fmax(mind4, mind5), a3 = fmax(mind6, mind7);
            tbv = fmax(fmax(a0, a1), fmax(a2, a3));
            dirty = false;

            const unsigned long long tb = (unsigned long long)__double_as_longlong(tbv);
            const unsigned thi = (unsigned)(tb >> 32);
            const unsigned tlo = (unsigned)tb;
            whi = wave_umax_rl(thi);

            // lo32: usually exactly one lane holds the hi-max -> readlane its
            // lo32 (scalar ops); exact ladder only on multi-lane hi ties.
            const unsigned long long own = __ballot(thi == whi);
            if (__popcll(own) == 1) {
                wlo = (unsigned)__builtin_amdgcn_readlane(
                          (int)tlo, (int)(__ffsll((unsigned long long)own) - 1));
            } else {
                wlo = wave_umax_rl(thi == whi ? tlo : 0u);
            }

            // per-lane min global idx among this lane's slots at the wave max
            // (numpy tie-break: scan high slot -> low, smallest wins last).
            n = 0x7fffffffu;
            if (thi == whi && tlo == wlo) {
                if (mind7 == tbv) n = tid + 7 * 1024;
                if (mind6 == tbv) n = tid + 6 * 1024;
                if (mind5 == tbv) n = tid + 5 * 1024;
                if (mind4 == tbv) n = tid + 4 * 1024;
                if (mind3 == tbv) n = tid + 3 * 1024;
                if (mind2 == tbv) n = tid + 2 * 1024;
                if (mind1 == tbv) n = tid + 1 * 1024;
                if (mind0 == tbv) n = tid;
            }
        }

        const unsigned long long mybits =
            ((unsigned long long)whi << 32) | (unsigned long long)wlo;
        const int buf = k & 1;
        if (lane == 0) atomicMax(&s_bmax[buf], mybits);
        __syncthreads();                                   // barrier A

        const unsigned long long bmaxbits = s_bmax[buf];
        if (tid == 0) {   // reset NEXT iter's slots (between barriers A and B)
            s_bmax[buf ^ 1] = 0ull;
            s_widx[buf ^ 1] = 0x7fffffff;
        }

        // --- owner LANES publish cached min idx directly (1-2 lanes typ.) ---
        if (mybits == bmaxbits && n != 0x7fffffffu)
            atomicMin(&s_widx[buf], (int)n);
        __syncthreads();                                   // barrier B

        // --- broadcast winner coords from LDS (same-addr = conflict-free) ---
        const int   widx = s_widx[buf];
        const float wx = s_pts[widx * 3 + 0];
        const float wy = s_pts[widx * 3 + 1];
        const float wz = s_pts[widx * 3 + 2];
        if (tid == 0) {
            idx_out[b * MSEL + k] = widx;
            float* o = dp + ((size_t)b * MSEL + k) * 3;
            o[0] = wx; o[1] = wy; o[2] = wz;
        }
        cx = wx; cy = wy; cz = wz;
    }
}

// One wave per selected row; lane i moves one float4 (64 * 16B = 1024B = full row).
__global__ void gather_kernel(const float* __restrict__ feats,  // [B, N, C]
                              const int* __restrict__ idx,      // [B, M]
                              float* __restrict__ df)           // [B, M, C]
{
    const int row  = blockIdx.x * 4 + (threadIdx.x >> 6);  // [0, B*M)
    const int lane = threadIdx.x & 63;
    const int b    = row >> 12;         // MSEL = 4096 rows per batch
    const int src  = idx[row];
    const float4* s = (const float4*)(feats + ((size_t)b * NPTS + src) * NFEAT);
    float4*       d = (float4*)(df + (size_t)row * NFEAT);
    d[lane] = s[lane];
}

extern "C" void kernel_launch(void* const* d_in, const int* in_sizes, int n_in,
                              void* d_out, int out_size, void* d_ws, size_t ws_size,
                              hipStream_t stream)
{
    const float* points   = (const float*)d_in[0];   // [8, 8192, 3]
    const float* features = (const float*)d_in[1];   // [8, 8192, 256]
    float* out = (float*)d_out;
    float* dp  = out;                                // [8, 4096, 3]
    float* df  = out + (size_t)BATCH * MSEL * 3;     // [8, 4096, 256]
    int*   idx_ws = (int*)d_ws;                      // [8, 4096] = 128 KB scratch

    fps_kernel<<<BATCH, BLOCK, 0, stream>>>(points, dp, idx_ws);
    gather_kernel<<<(BATCH * MSEL) / 4, 256, 0, stream>>>(features, idx_ws, df);
}

// Round 12
// 3925.462 us; speedup vs baseline: 1.5644x; 1.4057x over previous
//
#include <hip/hip_runtime.h>

// AdaptiveDownsampling: farthest point sampling (B=8, N=8192, m=4096) + gather.
// Outputs concatenated flat: dp [8,4096,3] then df [8,4096,256], float32.
//
// r2: np reference computes in float64 -> exact path must be fp64.
// r3-r5: register-array spill / AGPR tax lessons; named scalars only.
// r6: fp32 screen + rare exact fp64 path. 5275 us.
// r7: DPP wave max, packed-fp32 screen, precomputed margin. 4239 us.
// r8: FAILED (5264): redundant block reduce in every wave.
// r9: dirty-wave caching + fused v_max_u32_dpp ladders. 4198 us (BEST).
//     Clean counters: FETCH 424 KB / WRITE 512 KB, VGPR 64, VALU 1.56%.
// r10: FAILED (5165): Morton sort + sphere cull on the pacing path.
// r11: FAILED (6141): payload atomics (bundled changes).
// r12: FAILED (5532): bundled (a) running-min screen, (b) per-lane publish,
//     (c) ballot shortcut. VALU DOWN but time UP 32%.
// r13: waves_per_eu(4,4) on r12: counters BIT-IDENTICAL to r12 -> attribute
//     inert; "VGPR cliff" theory dead. r12's +192KB WRITE = 24B/thread ONCE
//     (prologue), not in-loop spill -> can't explain +1300us. One of r12's
//     three bundled changes is the poison; unknown which.
// r14: EXACT r9 base + ONE change (isolates r12's (c)): kill ladders 2+3 on
//     the common path. n (min idx at own thread max) computed branch-free
//     every dirty pass; hiown = ballot(thi==whi); popcount==1 (typical) ->
//     that lane owns the full wave max: wlo/wn via 2 readlanes, no ladder2,
//     no ladder3, no gate region. Exact fallback on multi-lane hi ties.
//     Saves ~90-100 cyc/iter on the pacing wave's serial reduce.
//     (Resubmit: GPU acquisition timeout.)

typedef float v2f __attribute__((ext_vector_type(2)));

#define BATCH 8
#define NPTS  8192
#define MSEL  4096
#define NFEAT 256
#define BLOCK 1024

// fp64 square, opaque to the compiler so no v_fma_f64 contraction can merge
// the following adds (numpy float64 does separate mul / add / add).
__device__ __forceinline__ double sqd(double x) {
    double r;
    asm("v_mul_f64 %0, %1, %1" : "=v"(r) : "v"(x));
    return r;
}

// Exact 64-lane u32 max via fused DPP max ops, result wave-uniform in SGPR.
// bound_ctrl:0 => out-of-range DPP sources read 0 (identity for unsigned max).
// Requires full exec / uniform control flow at the call site.
__device__ __forceinline__ unsigned wave_umax_rl(unsigned v) {
    unsigned s;
    asm volatile(
        "s_nop 1\n\t"
        "v_max_u32_dpp %1, %1, %1 row_shr:1  row_mask:0xf bank_mask:0xf bound_ctrl:0\n\t"
        "s_nop 1\n\t"
        "v_max_u32_dpp %1, %1, %1 row_shr:2  row_mask:0xf bank_mask:0xf bound_ctrl:0\n\t"
        "s_nop 1\n\t"
        "v_max_u32_dpp %1, %1, %1 row_shr:4  row_mask:0xf bank_mask:0xf bound_ctrl:0\n\t"
        "s_nop 1\n\t"
        "v_max_u32_dpp %1, %1, %1 row_shr:8  row_mask:0xf bank_mask:0xf bound_ctrl:0\n\t"
        "s_nop 1\n\t"
        "v_max_u32_dpp %1, %1, %1 row_bcast:15 row_mask:0xf bank_mask:0xf bound_ctrl:0\n\t"
        "s_nop 1\n\t"
        "v_max_u32_dpp %1, %1, %1 row_bcast:31 row_mask:0xf bank_mask:0xf bound_ctrl:0\n\t"
        "s_nop 1\n\t"
        "v_readlane_b32 %0, %1, 63"
        : "=s"(s), "+v"(v));
    return s;
}

__launch_bounds__(BLOCK, 1)
__global__ void fps_kernel(const float* __restrict__ pts,   // [B, N, 3]
                           float* __restrict__ dp,          // [B, M, 3]
                           int* __restrict__ idx_out)       // [B, M]
{
    __shared__ float s_pts[NPTS * 3];          // 96 KB fp32 copy (winner broadcast)
    __shared__ unsigned long long s_bmax[2];   // block max, double bits (nonneg)
    __shared__ int s_widx[2];                  // winner index via atomicMin

    const int b    = blockIdx.x;
    const int tid  = threadIdx.x;
    const int lane = tid & 63;
    const float* p = pts + (size_t)b * NPTS * 3;

    for (int i = tid; i < NPTS * 3; i += BLOCK) s_pts[i] = p[i];
    if (tid == 0) {
        s_bmax[0] = 0ull;        s_bmax[1] = 0ull;
        s_widx[0] = 0x7fffffff;  s_widx[1] = 0x7fffffff;
    }

    // Coords as float2 pairs (slots 2P, 2P+1) -> packed-fp32 screen.
    // mind (fp64 exact) + mfm (pre-margined fp32 screen threshold) per slot.
#define DECLP(P, J0, J1) \
    v2f pxp##P = { p[(tid + J0 * 1024) * 3 + 0], p[(tid + J1 * 1024) * 3 + 0] }; \
    v2f pyp##P = { p[(tid + J0 * 1024) * 3 + 1], p[(tid + J1 * 1024) * 3 + 1] }; \
    v2f pzp##P = { p[(tid + J0 * 1024) * 3 + 2], p[(tid + J1 * 1024) * 3 + 2] };
    DECLP(0, 0, 1) DECLP(1, 2, 3) DECLP(2, 4, 5) DECLP(3, 6, 7)
#undef DECLP
    double mind0 = 1e10, mind1 = 1e10, mind2 = 1e10, mind3 = 1e10;
    double mind4 = 1e10, mind5 = 1e10, mind6 = 1e10, mind7 = 1e10;
    float  mfm0 = 1.0001e10f, mfm1 = 1.0001e10f, mfm2 = 1.0001e10f, mfm3 = 1.0001e10f;
    float  mfm4 = 1.0001e10f, mfm5 = 1.0001e10f, mfm6 = 1.0001e10f, mfm7 = 1.0001e10f;

    // Selection 0 is point 0 (deterministic start).
    float cx = p[0], cy = p[1], cz = p[2];
    if (tid == 0) {
        dp[(size_t)b * MSEL * 3 + 0] = cx;
        dp[(size_t)b * MSEL * 3 + 1] = cy;
        dp[(size_t)b * MSEL * 3 + 2] = cz;
        idx_out[b * MSEL + 0] = 0;
    }

    double   tbv   = 0.0;          // cached thread-local max of mind0..7
    bool     dirty = true;         // lane updated since last wave reduce
    unsigned whi = 0u, wlo = 0u;   // cached wave max (double bits), SGPR
    unsigned wn  = 0x7fffffffu;    // cached wave min-index-at-max, SGPR

    __syncthreads();   // s_pts + slot inits visible

    for (int k = 1; k < MSEL; ++k) {
        const v2f cx2 = {cx, cx}, cy2 = {cy, cy}, cz2 = {cz, cz};

        // --- packed fp32 screen; exact fp64 update only on trigger (r9) ---
#define EX64(PX, PY, PZ, J) { \
        const double ddx = (double)(PX) - (double)cx; \
        const double ddy = (double)(PY) - (double)cy; \
        const double ddz = (double)(PZ) - (double)cz; \
        const double dd  = (sqd(ddx) + sqd(ddy)) + sqd(ddz); \
        if (dd < mind##J) { mind##J = dd; mfm##J = (float)dd * 1.0001f; dirty = true; } }
#define UPDP(P, J0, J1) { \
        const v2f dx = pxp##P - cx2, dy = pyp##P - cy2, dz = pzp##P - cz2; \
        const v2f d  = dx * dx + dy * dy + dz * dz; \
        if (d.x < mfm##J0) EX64(pxp##P.x, pyp##P.x, pzp##P.x, J0) \
        if (d.y < mfm##J1) EX64(pxp##P.y, pyp##P.y, pzp##P.y, J1) }
        UPDP(0, 0, 1) UPDP(1, 2, 3) UPDP(2, 4, 5) UPDP(3, 6, 7)
#undef UPDP
#undef EX64

        // --- wave reduce only if some lane in this wave updated ---
        if (__any(dirty)) {
            const double a0 = fmax(mind0, mind1), a1 = fmax(mind2, mind3);
            const double a2 = fmax(mind4, mind5), a3 = fmax(mind6, mind7);
            tbv = fmax(fmax(a0, a1), fmax(a2, a3));
            dirty = false;

            const unsigned long long tb = (unsigned long long)__double_as_longlong(tbv);
            const unsigned thi = (unsigned)(tb >> 32);
            const unsigned tlo = (unsigned)tb;
            whi = wave_umax_rl(thi);

            // per-lane min global idx among THIS lane's slots at its own max
            // (branch-free cndmask chain; numpy tie-break: scan high slot ->
            // low so the smallest index wins last assignment).
            unsigned n = 0x7fffffffu;
            if (mind7 == tbv) n = tid + 7 * 1024;
            if (mind6 == tbv) n = tid + 6 * 1024;
            if (mind5 == tbv) n = tid + 5 * 1024;
            if (mind4 == tbv) n = tid + 4 * 1024;
            if (mind3 == tbv) n = tid + 3 * 1024;
            if (mind2 == tbv) n = tid + 2 * 1024;
            if (mind1 == tbv) n = tid + 1 * 1024;
            if (mind0 == tbv) n = tid;

            // Single lane holds the hi-32 max (typical): that lane owns the
            // full wave max -> 2 readlanes replace ladder2 + ladder3 + gate.
            const unsigned long long hiown = __ballot(thi == whi);
            if (__popcll(hiown) == 1) {
                const int L = (int)(__ffsll(hiown) - 1);
                wlo = (unsigned)__builtin_amdgcn_readlane((int)tlo, L);
                wn  = (unsigned)__builtin_amdgcn_readlane((int)n,   L);
            } else {            // exact fallback on multi-lane hi ties
                wlo = wave_umax_rl(thi == whi ? tlo : 0u);
                const unsigned ng = (thi == whi && tlo == wlo) ? n : 0x7fffffffu;
                wn = ~wave_umax_rl(~ng);   // min over owner lanes
            }
        }

        const unsigned long long mybits =
            ((unsigned long long)whi << 32) | (unsigned long long)wlo;
        if (lane == 0) atomicMax(&s_bmax[k & 1], mybits);
        __syncthreads();                                   // barrier A

        const unsigned long long bmaxbits = s_bmax[k & 1];
        if (tid == 0) {   // reset NEXT iter's slots (between barriers A and B)
            s_bmax[(k + 1) & 1] = 0ull;
            s_widx[(k + 1) & 1] = 0x7fffffff;
        }

        // --- owner waves publish cached min index (one atomic per wave) ---
        if (lane == 0 && mybits == bmaxbits)
            atomicMin(&s_widx[k & 1], (int)wn);
        __syncthreads();                                   // barrier B

        // --- broadcast winner coords from LDS (same-addr = conflict-free) ---
        const int   widx = s_widx[k & 1];
        const float wx = s_pts[widx * 3 + 0];
        const float wy = s_pts[widx * 3 + 1];
        const float wz = s_pts[widx * 3 + 2];
        if (tid == 0) {
            idx_out[b * MSEL + k] = widx;
            float* o = dp + ((size_t)b * MSEL + k) * 3;
            o[0] = wx; o[1] = wy; o[2] = wz;
        }
        cx = wx; cy = wy; cz = wz;
    }
}

// One wave per selected row; lane i moves one float4 (64 * 16B = 1024B = full row).
__global__ void gather_kernel(const float* __restrict__ feats,  // [B, N, C]
                              const int* __restrict__ idx,      // [B, M]
                              float* __restrict__ df)           // [B, M, C]
{
    const int row  = blockIdx.x * 4 + (threadIdx.x >> 6);  // [0, B*M)
    const int lane = threadIdx.x & 63;
    const int b    = row >> 12;         // MSEL = 4096 rows per batch
    const int src  = idx[row];
    const float4* s = (const float4*)(feats + ((size_t)b * NPTS + src) * NFEAT);
    float4*       d = (float4*)(df + (size_t)row * NFEAT);
    d[lane] = s[lane];
}

extern "C" void kernel_launch(void* const* d_in, const int* in_sizes, int n_in,
                              void* d_out, int out_size, void* d_ws, size_t ws_size,
                              hipStream_t stream)
{
    const float* points   = (const float*)d_in[0];   // [8, 8192, 3]
    const float* features = (const float*)d_in[1];   // [8, 8192, 256]
    float* out = (float*)d_out;
    float* dp  = out;                                // [8, 4096, 3]
    float* df  = out + (size_t)BATCH * MSEL * 3;     // [8, 4096, 256]
    int*   idx_ws = (int*)d_ws;                      // [8, 4096] = 128 KB scratch

    fps_kernel<<<BATCH, BLOCK, 0, stream>>>(points, dp, idx_ws);
    gather_kernel<<<(BATCH * MSEL) / 4, 256, 0, stream>>>(features, idx_ws, df);
}